// Round 3
// baseline (18055.278 us; speedup 1.0000x reference)
//
#include <hip/hip_runtime.h>
#include <math.h>

// ---------------------------------------------------------------------------
// NetGIN forward on MI355X — round 3: fp16 activation store (was bf16).
// Activations live in ws as RAW (pre-BN) fp16; per-matrix S = {scale[128],
// shift[128]} fp32 applies BN on read (y = relu(x*sc+sh)). GEMM epilogues
// round to fp16 (RNE) and accumulate column stats FROM THE ROUNDED values,
// so BN exactly normalizes the stored tensors. All arithmetic fp32.
// ---------------------------------------------------------------------------

#define DEV_INLINE __device__ __forceinline__
typedef unsigned short u16;

union F16U { _Float16 h; u16 u; };
DEV_INLINE float h2f(u16 v){ F16U t; t.u = v; return (float)t.h; }
DEV_INLINE u16 f2h(float f){ F16U t; t.h = (_Float16)f; return t.u; }

DEV_INLINE float sigmoidf_(float x){ return 1.0f/(1.0f+expf(-x)); }
struct us2 { u16 x, y; };
struct us4 { u16 x, y, z, w; };

// ---------------- utility ----------------
__global__ void zero_k(float* __restrict__ p, int n){
  int i = blockIdx.x*256 + threadIdx.x;
  if (i < n) p[i] = 0.f;
}

// ---------------- CSR build ----------------
__global__ void count_deg(const int* __restrict__ dst, int* __restrict__ cnt, int E){
  int e = blockIdx.x*256 + threadIdx.x;
  if (e < E) atomicAdd(&cnt[dst[e]], 1);
}

__global__ void scan_excl(const int* __restrict__ cnt, int* __restrict__ offs, int N){
  const int* c = cnt + (size_t)blockIdx.x * N;
  int* o = offs + (size_t)blockIdx.x * (N+1);
  __shared__ int ps[1024];
  int t = threadIdx.x;
  int chunk = (N + 1023) >> 10;
  int lo = t*chunk, hi = min(lo+chunk, N);
  int s = 0;
  for (int i=lo;i<hi;++i) s += c[i];
  ps[t] = s; __syncthreads();
  for (int d=1; d<1024; d<<=1){
    int v = (t>=d) ? ps[t-d] : 0;
    __syncthreads();
    ps[t] += v;
    __syncthreads();
  }
  int pre = (t==0) ? 0 : ps[t-1];
  for (int i=lo;i<hi;++i){ o[i]=pre; pre += c[i]; }
  if (t==1023) o[N] = ps[1023];
}

__global__ void fill_csr(const int* __restrict__ src, const int* __restrict__ dst,
                         const int* __restrict__ offs, int* __restrict__ cur,
                         int* __restrict__ out, int E){
  int e = blockIdx.x*256 + threadIdx.x;
  if (e >= E) return;
  int d = dst[e];
  int pos = offs[d] + atomicAdd(&cur[d], 1);
  out[pos] = src[e];
}

__global__ void graph_offsets(const int* __restrict__ batch, int* __restrict__ goff, int N, int G){
  int g = blockIdx.x*blockDim.x + threadIdx.x;
  if (g > G) return;
  int lo=0, hi=N;
  while (lo<hi){ int mid=(lo+hi)>>1; if (batch[mid] < g) lo=mid+1; else hi=mid; }
  goff[g]=lo;
}

// ---------------- BN finalize: stats -> scale/shift, re-zero stats ----------------
__global__ void bnfin(float* __restrict__ stats, const float* __restrict__ g,
                      const float* __restrict__ be, float* __restrict__ S, float invN){
  int c = threadIdx.x;   // 128
  float m = stats[c]*invN;
  float v = stats[128+c]*invN - m*m;
  float sc = g[c]*rsqrtf(v + 1e-5f);
  S[c] = sc;
  S[128+c] = be[c] - m*sc;
  stats[c] = 0.f; stats[128+c] = 0.f;
}

// ---------------- main GEMM: C(N,128) = bnrelu(A)(N,K) @ W(K,128) + bias ----------------
// A: up to 4 fp16 parts (each N x 128). S per part (null => raw). C fp16 raw.
__global__ __launch_bounds__(256) void gemm_bn_hf(
  const u16* __restrict__ A0, const u16* __restrict__ A1,
  const u16* __restrict__ A2, const u16* __restrict__ A3,
  const float* __restrict__ S0, const float* __restrict__ S1,
  const float* __restrict__ S2, const float* __restrict__ S3,
  const float* __restrict__ W, const float* __restrict__ bias,
  u16* __restrict__ C, float* __restrict__ stats,
  int N, int npart)
{
  __shared__ float As[64][20];
  __shared__ float Ws[16][128];
  __shared__ float red[8][128];
  const u16* Ap[4] = {A0,A1,A2,A3};
  const float* Sp[4] = {S0,S1,S2,S3};
  int t = threadIdx.x;
  int tx = t & 31, ty = t >> 5;
  int row0 = blockIdx.x * 64;
  float acc[8][4];
  #pragma unroll
  for (int i=0;i<8;++i)
    #pragma unroll
    for (int j=0;j<4;++j) acc[i][j]=0.f;
  int K = npart << 7;
  int ar = t >> 2;            // 0..63 row in tile
  int ak = (t & 3) << 2;      // k offset 0,4,8,12
  for (int k0=0; k0<K; k0+=16){
    int part = k0 >> 7;
    int kl = k0 & 127;
    const u16* A = Ap[part];
    const float* S = Sp[part];
    { // stage A 64x16 with bn+relu prologue
      int row = row0 + ar;
      float v0=0.f,v1=0.f,v2=0.f,v3=0.f;
      if (row < N){
        us4 u = *(const us4*)(A + (size_t)row*128 + kl + ak);
        v0=h2f(u.x); v1=h2f(u.y); v2=h2f(u.z); v3=h2f(u.w);
      }
      if (S){
        const float* sc = S + kl + ak;
        const float* sh = S + 128 + kl + ak;
        v0 = fmaxf(fmaf(v0, sc[0], sh[0]), 0.f);
        v1 = fmaxf(fmaf(v1, sc[1], sh[1]), 0.f);
        v2 = fmaxf(fmaf(v2, sc[2], sh[2]), 0.f);
        v3 = fmaxf(fmaf(v3, sc[3], sh[3]), 0.f);
      }
      float4 v = make_float4(v0,v1,v2,v3);
      *(float4*)(&As[ar][ak]) = v;
    }
    { // stage W 16x128
      int base = t << 3;
      int kr = base >> 7, cc = base & 127;
      const float* Wp = W + (size_t)(k0+kr)*128 + cc;
      float4 w0 = *(const float4*)(Wp);
      float4 w1 = *(const float4*)(Wp + 4);
      *(float4*)(&Ws[kr][cc]) = w0;
      *(float4*)(&Ws[kr][cc+4]) = w1;
    }
    __syncthreads();
    #pragma unroll
    for (int k=0;k<16;k+=2){
      float4 w0 = *(const float4*)(&Ws[k][tx<<2]);
      float4 w1 = *(const float4*)(&Ws[k+1][tx<<2]);
      #pragma unroll
      for (int i=0;i<8;++i){
        float2 a = *(const float2*)(&As[(ty<<3)+i][k]);
        acc[i][0] = fmaf(a.x, w0.x, acc[i][0]);
        acc[i][1] = fmaf(a.x, w0.y, acc[i][1]);
        acc[i][2] = fmaf(a.x, w0.z, acc[i][2]);
        acc[i][3] = fmaf(a.x, w0.w, acc[i][3]);
        acc[i][0] = fmaf(a.y, w1.x, acc[i][0]);
        acc[i][1] = fmaf(a.y, w1.y, acc[i][1]);
        acc[i][2] = fmaf(a.y, w1.z, acc[i][2]);
        acc[i][3] = fmaf(a.y, w1.w, acc[i][3]);
      }
    }
    __syncthreads();
  }
  // epilogue: +bias, round fp16, store, stats from rounded values
  int c0 = tx << 2;
  float4 b4 = *(const float4*)(bias + c0);
  float s1[4] = {0,0,0,0}, s2[4] = {0,0,0,0};
  #pragma unroll
  for (int i=0;i<8;++i){
    int row = row0 + (ty<<3) + i;
    if (row < N){
      us4 o;
      o.x = f2h(acc[i][0] + b4.x);
      o.y = f2h(acc[i][1] + b4.y);
      o.z = f2h(acc[i][2] + b4.z);
      o.w = f2h(acc[i][3] + b4.w);
      *(us4*)(C + (size_t)row*128 + c0) = o;
      float r0=h2f(o.x), r1=h2f(o.y), r2=h2f(o.z), r3=h2f(o.w);
      s1[0]+=r0; s1[1]+=r1; s1[2]+=r2; s1[3]+=r3;
      s2[0]+=r0*r0; s2[1]+=r1*r1; s2[2]+=r2*r2; s2[3]+=r3*r3;
    }
  }
  #pragma unroll
  for (int j=0;j<4;++j) red[ty][c0+j] = s1[j];
  __syncthreads();
  if (ty==0){
    #pragma unroll
    for (int j=0;j<4;++j){
      float tot=0.f;
      #pragma unroll
      for (int yy=0;yy<8;++yy) tot += red[yy][c0+j];
      atomicAdd(&stats[c0+j], tot);
    }
  }
  __syncthreads();
  #pragma unroll
  for (int j=0;j<4;++j) red[ty][c0+j] = s2[j];
  __syncthreads();
  if (ty==0){
    #pragma unroll
    for (int j=0;j<4;++j){
      float tot=0.f;
      #pragma unroll
      for (int yy=0;yy<8;++yy) tot += red[yy][c0+j];
      atomicAdd(&stats[128+c0+j], tot);
    }
  }
}

// ---------------- small-K encoder GEMM (fp32 inputs, K <= 26) ----------------
__global__ __launch_bounds__(256) void gemm_enc(
  const float* __restrict__ X0, int w0, const float* __restrict__ X1, int w1,
  const float* __restrict__ W, const float* __restrict__ bias,
  u16* __restrict__ C, float* __restrict__ stats, int N)
{
  __shared__ float Ws[26*128];
  __shared__ float red[256];
  int K = w0 + w1;
  int t = threadIdx.x;
  for (int i=t;i<K*128;i+=256) Ws[i] = W[i];
  __syncthreads();
  int c = t & 127, rh = t >> 7;
  float b = bias[c];
  float s1=0.f, s2=0.f;
  for (int r0 = blockIdx.x*2; r0 < N; r0 += gridDim.x*2){
    int r = r0 + rh;
    if (r < N){
      float acc = b;
      for (int k=0;k<w0;++k) acc = fmaf(X0[(size_t)r*w0+k], Ws[k*128+c], acc);
      for (int k=0;k<w1;++k) acc = fmaf(X1[(size_t)r*w1+k], Ws[(w0+k)*128+c], acc);
      u16 o = f2h(acc);
      C[(size_t)r*128+c] = o;
      float rv = h2f(o);
      s1 += rv; s2 += rv*rv;
    }
  }
  red[t] = s1; __syncthreads();
  if (t < 128) atomicAdd(&stats[t], red[t] + red[t+128]);
  __syncthreads();
  red[t] = s2; __syncthreads();
  if (t < 128) atomicAdd(&stats[128+t], red[t] + red[t+128]);
}

// ---------------- GIN aggregation ----------------
// Z = (1+eps)*bnrelu(X_i) + sum_{j in N(i)} bnrelu(X_j); fp16 in/out.
__global__ __launch_bounds__(256) void aggregate_hf(
  const u16* __restrict__ X, const float* __restrict__ S,
  const int* __restrict__ srcs, const int* __restrict__ offs,
  const float* __restrict__ geps, int gi, u16* __restrict__ Z, int N)
{
  int i = blockIdx.x*4 + (threadIdx.x>>6);
  int ln = threadIdx.x & 63;
  int c = ln*2;
  if (i >= N) return;
  float sca = S[c], sha = S[128+c];
  float scb = S[c+1], shb = S[128+c+1];
  float eps1 = 1.0f + geps[gi];
  us2 x0 = *(const us2*)(X + (size_t)i*128 + c);
  float acca = eps1 * fmaxf(fmaf(h2f(x0.x), sca, sha), 0.f);
  float accb = eps1 * fmaxf(fmaf(h2f(x0.y), scb, shb), 0.f);
  int e0 = offs[i], e1 = offs[i+1];
  for (int e=e0; e<e1; ++e){
    int s = srcs[e];
    us2 xv = *(const us2*)(X + (size_t)s*128 + c);
    acca += fmaxf(fmaf(h2f(xv.x), sca, sha), 0.f);
    accb += fmaxf(fmaf(h2f(xv.y), scb, shb), 0.f);
  }
  us2 o; o.x = f2h(acca); o.y = f2h(accb);
  *(us2*)(Z + (size_t)i*128 + c) = o;
}

// ---------------- Set2Set ----------------
__global__ __launch_bounds__(256) void lstm_step(
  float* __restrict__ q_star, float* __restrict__ h, float* __restrict__ cst,
  const float* __restrict__ Wih, const float* __restrict__ Whh,
  const float* __restrict__ bih, const float* __restrict__ bhh, int G)
{
  __shared__ float q[256], hh[128], z[512];
  int t = threadIdx.x;
  for (int g = blockIdx.x; g < G; g += gridDim.x){
    q[t] = q_star[(size_t)g*256 + t];
    if (t < 128) hh[t] = h[(size_t)g*128 + t];
    __syncthreads();
    #pragma unroll
    for (int p=0;p<2;++p){
      int j = t + 256*p;
      float acc = bih[j] + bhh[j];
      const float* wi = Wih + (size_t)j*256;
      const float* wh = Whh + (size_t)j*128;
      for (int k=0;k<256;++k) acc = fmaf(q[k], wi[k], acc);
      for (int k=0;k<128;++k) acc = fmaf(hh[k], wh[k], acc);
      z[j] = acc;
    }
    __syncthreads();
    if (t < 128){
      float i_ = z[t], f_ = z[128+t], g_ = z[256+t], o_ = z[384+t];
      float cc = sigmoidf_(f_)*cst[(size_t)g*128+t] + sigmoidf_(i_)*tanhf(g_);
      float hn = sigmoidf_(o_)*tanhf(cc);
      cst[(size_t)g*128+t] = cc;
      h[(size_t)g*128+t]  = hn;
      q_star[(size_t)g*256+t] = hn;
    }
    __syncthreads();
  }
}

__global__ __launch_bounds__(256) void dot_h_hf(
  const u16* __restrict__ X, const float* __restrict__ S,
  const float* __restrict__ h, const int* __restrict__ batch,
  float* __restrict__ e, int N)
{
  int wv = threadIdx.x >> 6, ln = threadIdx.x & 63;
  int i = blockIdx.x*4 + wv;
  if (i >= N) return;
  int g = batch[i];
  int c = ln*2;
  us2 x2 = *(const us2*)(X + (size_t)i*128 + c);
  float2 h2 = *(const float2*)(h + (size_t)g*128 + c);
  float xa = fmaxf(fmaf(h2f(x2.x), S[c],   S[128+c]),   0.f);
  float xb = fmaxf(fmaf(h2f(x2.y), S[c+1], S[128+c+1]), 0.f);
  float p = xa*h2.x + xb*h2.y;
  #pragma unroll
  for (int off=32; off; off>>=1) p += __shfl_down(p, off, 64);
  if (ln==0) e[i] = p;
}

__global__ __launch_bounds__(256) void seg_reduce(
  const float* __restrict__ e, const int* __restrict__ goff,
  float* __restrict__ emax, float* __restrict__ invden, int G)
{
  int g = blockIdx.x;
  int lo = goff[g], hi = goff[g+1];
  int t = threadIdx.x;
  __shared__ float red[256];
  float m = -3.4e38f;
  for (int i=lo+t; i<hi; i+=256) m = fmaxf(m, e[i]);
  red[t] = m; __syncthreads();
  for (int d=128; d; d>>=1){ if (t<d) red[t] = fmaxf(red[t], red[t+d]); __syncthreads(); }
  m = red[0]; __syncthreads();
  float s = 0.f;
  for (int i=lo+t; i<hi; i+=256) s += expf(e[i]-m);
  red[t] = s; __syncthreads();
  for (int d=128; d; d>>=1){ if (t<d) red[t] += red[t+d]; __syncthreads(); }
  if (t==0){
    emax[g] = m;
    invden[g] = (hi>lo && red[0]>0.f) ? 1.f/red[0] : 0.f;
  }
}

__global__ __launch_bounds__(128) void r_kernel_hf(
  const u16* __restrict__ X, const float* __restrict__ S,
  const float* __restrict__ e, const int* __restrict__ goff,
  const float* __restrict__ emax, const float* __restrict__ invden,
  float* __restrict__ q_star, int G)
{
  int g = blockIdx.x, c = threadIdx.x;
  int lo = goff[g], hi = goff[g+1];
  float m = emax[g], inv = invden[g];
  float sc = S[c], sh = S[128+c];
  float r = 0.f;
  for (int i=lo; i<hi; ++i){
    float w = expf(e[i]-m);
    r = fmaf(w, fmaxf(fmaf(h2f(X[(size_t)i*128+c]), sc, sh), 0.f), r);
  }
  q_star[(size_t)g*256 + 128 + c] = r*inv;
}

__global__ __launch_bounds__(128) void final_k(
  const float* __restrict__ q_star, const float* __restrict__ fc1W,
  const float* __restrict__ fc1b, const float* __restrict__ fc4W,
  const float* __restrict__ fc4b, float* __restrict__ out, int G)
{
  __shared__ float q[256];
  __shared__ float h1[128];
  int g = blockIdx.x, t = threadIdx.x;
  q[t]     = q_star[(size_t)g*256 + t];
  q[128+t] = q_star[(size_t)g*256 + 128 + t];
  __syncthreads();
  float acc = fc1b[t];
  for (int k=0;k<256;++k) acc = fmaf(q[k], fc1W[(size_t)k*128+t], acc);
  h1[t] = fmaxf(acc, 0.f);
  __syncthreads();
  if (t < 12){
    float o = fc4b[t];
    for (int d=0; d<128; ++d) o = fmaf(h1[d], fc4W[(size_t)d*12+t], o);
    out[(size_t)g*12+t] = o;
  }
}

// ---------------------------------------------------------------------------
extern "C" void kernel_launch(void* const* d_in, const int* in_sizes, int n_in,
                              void* d_out, int out_size, void* d_ws, size_t ws_size,
                              hipStream_t stream)
{
  (void)n_in; (void)ws_size;
  const int N = in_sizes[0] / 3;
  const int E = in_sizes[62] / 2;
  const int G = out_size / 12;

  auto P = [&](int i){ return (const float*)d_in[i]; };
  const float* gW1 = P(37); const float* gb1 = P(38); const float* gg1 = P(39); const float* gbe1 = P(40);
  const float* gW2 = P(41); const float* gb2 = P(42); const float* gg2 = P(43); const float* gbe2 = P(44);
  const float* geps = P(45);
  const float* mW1 = P(46); const float* mb1 = P(47); const float* mg1 = P(48); const float* mbe1 = P(49);
  const float* mW2 = P(50); const float* mb2 = P(51); const float* mg2 = P(52); const float* mbe2 = P(53);
  const int* ei[4] = {(const int*)d_in[62], (const int*)d_in[63],
                      (const int*)d_in[64], (const int*)d_in[65]};
  const int* batch = (const int*)d_in[66];

  char* ws = (char*)d_ws;
  size_t off = 0;
  auto alloc = [&](size_t bytes)->char*{
    char* p = ws + off;
    off = (off + bytes + 255) & ~(size_t)255;
    return p;
  };
  u16* X = (u16*)alloc((size_t)N*128*2);              // also the MLP intermediate
  u16* Z[4]; for (int k=0;k<4;++k) Z[k] = (u16*)alloc((size_t)N*128*2);
  float* ebuf  = (float*)alloc((size_t)N*4);
  float* stats = (float*)alloc(256*4);
  float* Sb    = (float*)alloc(6*256*4);
  int* offs4 = (int*)alloc((size_t)4*(N+1)*4);
  int* srcs4 = (int*)alloc((size_t)4*E*4);
  int* cnt4  = (int*)alloc((size_t)4*N*4);
  int* goff  = (int*)alloc((size_t)(G+1)*4);
  float* qstar = (float*)alloc((size_t)G*256*4);
  float* hbuf  = (float*)alloc((size_t)G*128*4);
  float* cbuf  = (float*)alloc((size_t)G*128*4);
  float* emax  = (float*)alloc((size_t)G*4);
  float* invden= (float*)alloc((size_t)G*4);

  const float invN = 1.0f / (float)N;
  const int ST = 0, SX = 1, SZ0 = 2;
  auto Sl = [&](int i){ return Sb + (size_t)i*256; };

  // ---- CSR build ----
  int zgrid = (4*N + 255)/256;
  zero_k<<<zgrid,256,0,stream>>>((float*)cnt4, 4*N);
  int egrid = (E + 255)/256;
  for (int l=0;l<4;++l)
    count_deg<<<egrid,256,0,stream>>>(ei[l]+E, cnt4 + (size_t)l*N, E);
  scan_excl<<<4,1024,0,stream>>>(cnt4, offs4, N);
  zero_k<<<zgrid,256,0,stream>>>((float*)cnt4, 4*N);
  for (int l=0;l<4;++l)
    fill_csr<<<egrid,256,0,stream>>>(ei[l], ei[l]+E, offs4 + (size_t)l*(N+1),
                                     cnt4 + (size_t)l*N, srcs4 + (size_t)l*E, E);
  graph_offsets<<<(G+1+255)/256,256,0,stream>>>(batch, goff, N, G);
  zero_k<<<1,256,0,stream>>>(stats, 256);

  int ggrid = (N + 63)/64;
  auto run_bnfin = [&](const float* g, const float* be, float* S){
    bnfin<<<1,128,0,stream>>>(stats, g, be, S, invN);
  };
  auto run_gemm1 = [&](const u16* A, const float* S, const float* W, const float* b, u16* Cc){
    gemm_bn_hf<<<ggrid,256,0,stream>>>(A,nullptr,nullptr,nullptr, S,nullptr,nullptr,nullptr,
                                       W,b,Cc,stats,N,1);
  };

  // ---- encoders (X doubles as the intermediate T) ----
  gemm_enc<<<1024,256,0,stream>>>(P(0),3, nullptr,0, P(5), P(6), X, stats, N);
  run_bnfin(P(7), P(8), Sl(ST));
  run_gemm1(X, Sl(ST), P(9), P(10), Z[0]);
  run_bnfin(P(11), P(12), Sl(SZ0+0));

  gemm_enc<<<1024,256,0,stream>>>(P(1),13, P(2),13, P(13), P(14), X, stats, N);
  run_bnfin(P(15), P(16), Sl(ST));
  run_gemm1(X, Sl(ST), P(17), P(18), Z[1]);
  run_bnfin(P(19), P(20), Sl(SZ0+1));

  gemm_enc<<<1024,256,0,stream>>>(P(3),4, P(4),1, P(21), P(22), X, stats, N);
  run_bnfin(P(23), P(24), Sl(ST));
  run_gemm1(X, Sl(ST), P(25), P(26), Z[2]);
  run_bnfin(P(27), P(28), Sl(SZ0+2));

  // m0: concat [nl, na, ea] = Z0,Z1,Z2
  gemm_bn_hf<<<ggrid,256,0,stream>>>(Z[0],Z[1],Z[2],nullptr,
                                     Sl(SZ0+0),Sl(SZ0+1),Sl(SZ0+2),nullptr,
                                     P(29), P(30), X, stats, N, 3);
  run_bnfin(P(31), P(32), Sl(ST));
  run_gemm1(X, Sl(ST), P(33), P(34), X);        // in-place (row-exclusive blocks)
  run_bnfin(P(35), P(36), Sl(SX));

  // ---- 6 GIN layers ----
  int agrid = (N + 3)/4;
  for (int L=0; L<6; ++L){
    // all 4 aggregates first (they read X; X becomes scratch afterwards)
    for (int k=0;k<4;++k){
      int gi = 4*L + k;
      aggregate_hf<<<agrid,256,0,stream>>>(X, Sl(SX), srcs4 + (size_t)k*E,
                                           offs4 + (size_t)k*(N+1), geps, gi, Z[k], N);
    }
    for (int k=0;k<4;++k){
      int gi = 4*L + k;
      run_gemm1(Z[k], nullptr, gW1 + (size_t)gi*128*128, gb1 + (size_t)gi*128, X);
      run_bnfin(gg1 + (size_t)gi*128, gbe1 + (size_t)gi*128, Sl(ST));
      run_gemm1(X, Sl(ST), gW2 + (size_t)gi*128*128, gb2 + (size_t)gi*128, Z[k]);
      run_bnfin(gg2 + (size_t)gi*128, gbe2 + (size_t)gi*128, Sl(SZ0+k));
    }
    // fusion: concat [x1, x3, x2, x4] = Z0, Z2, Z1, Z3
    gemm_bn_hf<<<ggrid,256,0,stream>>>(Z[0],Z[2],Z[1],Z[3],
                                       Sl(SZ0+0),Sl(SZ0+2),Sl(SZ0+1),Sl(SZ0+3),
                                       mW1 + (size_t)L*512*128, mb1 + (size_t)L*128, X, stats, N, 4);
    run_bnfin(mg1 + (size_t)L*128, mbe1 + (size_t)L*128, Sl(ST));
    run_gemm1(X, Sl(ST), mW2 + (size_t)L*128*128, mb2 + (size_t)L*128, X);  // in-place
    run_bnfin(mg2 + (size_t)L*128, mbe2 + (size_t)L*128, Sl(SX));
  }

  // ---- Set2Set (6 steps) ----
  zero_k<<<(G*256+255)/256,256,0,stream>>>(qstar, G*256);
  zero_k<<<(G*128+255)/256,256,0,stream>>>(hbuf, G*128);
  zero_k<<<(G*128+255)/256,256,0,stream>>>(cbuf, G*128);
  int dgrid = (N + 3)/4;
  for (int s=0;s<6;++s){
    lstm_step<<<64,256,0,stream>>>(qstar, hbuf, cbuf, P(54), P(55), P(56), P(57), G);
    dot_h_hf<<<dgrid,256,0,stream>>>(X, Sl(SX), hbuf, batch, ebuf, N);
    seg_reduce<<<G,256,0,stream>>>(ebuf, goff, emax, invden, G);
    r_kernel_hf<<<G,128,0,stream>>>(X, Sl(SX), ebuf, goff, emax, invden, qstar, G);
  }

  final_k<<<G,128,0,stream>>>(qstar, P(58), P(59), P(60), P(61), (float*)d_out, G);
}